// Round 8
// baseline (20.063 us; speedup 1.0000x reference)
//
#include <hip/hip_runtime.h>

// FeatureViewEncoder: per-feature Conv1d(1,H,3) + mask + max-over-time.
// out[b,f,h] = max_{l: mask[b,l]!=0} ( sum_k x[b,l+k,f]*w[f,h,k] + bias[f,h] ), else -1e9.
//
// R8 PROBE: exact R6 kernel logic, but the grid is split into TWO sequential
// half-launches (b in [0,64) and [64,128)). Work is identical to R6's single
// launch (16.17 us). Measured dur = F + 2*O + K6 (+eps) vs R6's F + O + K6:
//   - dur ~26-28us  -> per-node overhead O ~ 10us dominates; single launch is
//                      already optimal; kernel internals are irrelevant.
//   - dur ~17.5-18.5 -> O small; kernel truly ~10us; optimize critical path.

#define NEG_INF_F (-1e9f)

typedef float v2f __attribute__((ext_vector_type(2)));

constexpr int B_ = 128;
constexpr int V_ = 200;
constexpr int F_ = 64;
constexpr int H_ = 128;
constexpr int L_ = V_ - 3 + 1;   // 198

constexpr int NTHR = 256;
constexpr int FG   = 8;                    // features per block
constexpr int HPT  = 8;                    // h-outputs per thread (4 packed pairs)
constexpr int MAXW = (L_ + 7) & ~7;        // 200: max windows, mult of 8
constexpr int WSTR = 4 * MAXW + 8;         // 808 floats: 808%32==8 -> f-rows 8 banks apart

__global__ __launch_bounds__(NTHR)
void fve_kernel(const float* __restrict__ x,     // [B,V,F]
                const int*   __restrict__ mask,  // [B,1,L]
                const float* __restrict__ w,     // [F,H,K]
                const float* __restrict__ bias,  // [F,H]
                float* __restrict__ out,         // [B,F,H]
                int b_base)
{
    __shared__ __align__(16) float xc[FG][WSTR];  // compacted windows: xc[f][4j+k]
    __shared__ int vlist[L_];
    __shared__ int vcnt;

    const int b  = b_base + (blockIdx.x >> 3);   // half-grid: 512 blocks = 64 b
    const int f0 = (blockIdx.x & 7) * FG;
    const int t  = threadIdx.x;

    if (t == 0) vcnt = 0;
    __syncthreads();

    // Phase A: compact valid time-steps (order irrelevant for max).
    if (t < L_ && mask[b * L_ + t] != 0) {
        const int p = atomicAdd(&vcnt, 1);
        vlist[p] = t;
    }
    __syncthreads();

    const int n    = vcnt;
    const int npad = (n + 7) & ~7;   // mult of 8 (dup window 0; max is idempotent)

    // Phase B: build stride-4 windows straight from global:
    //   xc[fq*4+c][4j+k] = x[b, l_j+k, f0+fq*4+c], k=0..2 (slot 3 = pad).
    for (int item = t; item < npad * 8; item += NTHR) {
        const int j    = item >> 3;
        const int k    = (item >> 1) & 3;
        const int half = item & 1;
        if (k == 3) continue;
        const int l = (j < n) ? vlist[j] : vlist[0];
        const float4 g = *reinterpret_cast<const float4*>(
            x + ((size_t)b * V_ + l + k) * F_ + f0 + half * 4);
        const int col = 4 * j + k;
        xc[half * 4 + 0][col] = g.x;
        xc[half * 4 + 1][col] = g.y;
        xc[half * 4 + 2][col] = g.z;
        xc[half * 4 + 3][col] = g.w;
    }
    __syncthreads();

    // Thread map: wave covers 2 f-rows; 16 h-lanes x 2 l-lanes per f.
    const int f_local = t >> 5;            // 0..7
    const int f       = f0 + f_local;
    const int h_lane  = (t >> 1) & 15;
    const int h0      = h_lane * HPT;      // 0,8,...,120
    const int l_lane  = t & 1;

    // Weights for h0..h0+7 repacked into h-pairs (layout in mem: [h][k]).
    const float* wp = w + ((size_t)f * H_ + h0) * 3;
    float wt[24];
#pragma unroll
    for (int j = 0; j < 6; ++j)
        *reinterpret_cast<float4*>(&wt[j * 4]) =
            *reinterpret_cast<const float4*>(wp + j * 4);

    float bsc[8];
    *reinterpret_cast<float4*>(&bsc[0]) =
        *reinterpret_cast<const float4*>(bias + (size_t)f * H_ + h0);
    *reinterpret_cast<float4*>(&bsc[4]) =
        *reinterpret_cast<const float4*>(bias + (size_t)f * H_ + h0 + 4);

    v2f wp0[4], wp1[4], wp2[4], bpk[4], mpk[4];
#pragma unroll
    for (int p = 0; p < 4; ++p) {
        wp0[p] = (v2f){wt[6 * p + 0], wt[6 * p + 3]};
        wp1[p] = (v2f){wt[6 * p + 1], wt[6 * p + 4]};
        wp2[p] = (v2f){wt[6 * p + 2], wt[6 * p + 5]};
        bpk[p] = (v2f){bsc[2 * p], bsc[2 * p + 1]};
        mpk[p] = (v2f){NEG_INF_F, NEG_INF_F};
    }

    const float4* xq = reinterpret_cast<const float4*>(&xc[f_local][0]);

#define PROCQ(Q)                                                              \
    do {                                                                      \
        const v2f X0 = (v2f){(Q).x, (Q).x};                                   \
        const v2f X1 = (v2f){(Q).y, (Q).y};                                   \
        const v2f X2 = (v2f){(Q).z, (Q).z};                                   \
        _Pragma("unroll")                                                     \
        for (int p = 0; p < 4; ++p) {                                         \
            const v2f c = __builtin_elementwise_fma(X0, wp0[p],               \
                          __builtin_elementwise_fma(X1, wp1[p],               \
                          __builtin_elementwise_fma(X2, wp2[p], bpk[p])));    \
            mpk[p] = __builtin_elementwise_max(mpk[p], c);                    \
        }                                                                     \
    } while (0)

    for (int u = 0; u < npad; u += 8) {
        const int i0 = u + l_lane;
        const float4 q0 = xq[i0];
        const float4 q1 = xq[i0 + 2];
        const float4 q2 = xq[i0 + 4];
        const float4 q3 = xq[i0 + 6];
        PROCQ(q0);
        PROCQ(q1);
        PROCQ(q2);
        PROCQ(q3);
    }
#undef PROCQ

    // Reduce across the l_lane pair (lanes t, t^1 hold same (f,h0)).
#pragma unroll
    for (int p = 0; p < 4; ++p) {
        const float a = __shfl_xor(mpk[p].x, 1, 64);
        const float c = __shfl_xor(mpk[p].y, 1, 64);
        mpk[p].x = fmaxf(mpk[p].x, a);
        mpk[p].y = fmaxf(mpk[p].y, c);
    }

    // l_lane 0 -> h0..h0+3, l_lane 1 -> h0+4..h0+7.
    float* op = out + ((size_t)b * F_ + f) * H_ + h0 + l_lane * 4;
    const int pb = l_lane * 2;
    *reinterpret_cast<float4*>(op) =
        make_float4(mpk[pb].x, mpk[pb].y, mpk[pb + 1].x, mpk[pb + 1].y);
}

extern "C" void kernel_launch(void* const* d_in, const int* in_sizes, int n_in,
                              void* d_out, int out_size, void* d_ws, size_t ws_size,
                              hipStream_t stream) {
    const float* x    = (const float*)d_in[0];  // input_visit
    const int*   mask = (const int*)d_in[1];    // visit_mask
    const float* w    = (const float*)d_in[2];  // conv_w
    const float* bias = (const float*)d_in[3];  // conv_b
    float* out = (float*)d_out;

    const int half_grid = (B_ / 2) * (F_ / FG);  // 512 blocks each
    fve_kernel<<<half_grid, NTHR, 0, stream>>>(x, mask, w, bias, out, 0);
    fve_kernel<<<half_grid, NTHR, 0, stream>>>(x, mask, w, bias, out, B_ / 2);
}

// Round 9
// 18.311 us; speedup vs baseline: 1.0957x; 1.0957x over previous
//
#include <hip/hip_runtime.h>

// FeatureViewEncoder: per-feature Conv1d(1,H,3) + mask + max-over-time.
// out[b,f,h] = max_{l: mask[b,l]!=0} ( sum_k x[b,l+k,f]*w[f,h,k] + bias[f,h] ), else -1e9.
//
// R9: R6's occupancy (FG=8, grid=1024, 4 blocks/CU) + halved main-loop LDS
// instruction count via wave = 2f x 8h x 4l (HPT=16): 416 ds_read_b128/CU
// (~2.1us) < VALU (~2.8us) -> VALU becomes the binding constraint.
// WSTR % 32 == 16: the wave's 2 f-rows sit 16 banks apart; 4 l-lanes x
// 4-bank quads tile each half -> conflict-free b128 reads.
// Ballot-based compaction (4 atomics/block, not 99 serial).

#define NEG_INF_F (-1e9f)

typedef float v2f __attribute__((ext_vector_type(2)));

constexpr int B_ = 128;
constexpr int V_ = 200;
constexpr int F_ = 64;
constexpr int H_ = 128;
constexpr int L_ = V_ - 3 + 1;   // 198

constexpr int NTHR = 256;
constexpr int FG   = 8;                    // features per block
constexpr int HPT  = 16;                   // h-outputs per thread (8 packed pairs)
constexpr int MAXW = (L_ + 15) & ~15;      // 208: max windows, mult of 16
constexpr int WSTR = 4 * MAXW + 16;        // 848 floats; 848%32==16

__global__ __launch_bounds__(NTHR)
void fve_kernel(const float* __restrict__ x,     // [B,V,F]
                const int*   __restrict__ mask,  // [B,1,L]
                const float* __restrict__ w,     // [F,H,K]
                const float* __restrict__ bias,  // [F,H]
                float* __restrict__ out)         // [B,F,H]
{
    __shared__ __align__(16) float xc[FG][WSTR];  // compacted windows: xc[f][4j+k]
    __shared__ int vlist[MAXW];
    __shared__ int vcnt;

    const int b  = blockIdx.x >> 3;        // grid = B * (F/FG) = 1024
    const int f0 = (blockIdx.x & 7) * FG;
    const int t  = threadIdx.x;
    const int lane = t & 63;

    // Thread map (main loop): wave = 2 f-rows x 8 h-lanes x 4 l-lanes.
    const int f_sub   = lane >> 5;          // 0..1
    const int h_lane  = (lane >> 2) & 7;    // 0..7
    const int l_lane  = lane & 3;           // 0..3
    const int f_local = (t >> 6) * 2 + f_sub;  // 0..7
    const int f       = f0 + f_local;
    const int h0      = h_lane * HPT;       // 0,16,...,112

    if (t == 0) vcnt = 0;

    // Hoist weight/bias global loads: issue before phase A so HBM latency
    // overlaps the mask read + compaction.
    const float* wp = w + ((size_t)f * H_ + h0) * 3;
    float wt[48];
#pragma unroll
    for (int j = 0; j < 12; ++j)
        *reinterpret_cast<float4*>(&wt[j * 4]) =
            *reinterpret_cast<const float4*>(wp + j * 4);

    float bsc[16];
#pragma unroll
    for (int j = 0; j < 4; ++j)
        *reinterpret_cast<float4*>(&bsc[j * 4]) =
            *reinterpret_cast<const float4*>(bias + (size_t)f * H_ + h0 + j * 4);

    __syncthreads();   // vcnt=0 visible

    // Phase A: ballot-compaction of valid time-steps (order irrelevant for max).
    {
        const bool valid = (t < L_) && (mask[b * L_ + t] != 0);
        const unsigned long long bal = __ballot(valid);
        int base = 0;
        if (lane == 0) base = atomicAdd(&vcnt, __popcll(bal));
        base = __shfl(base, 0, 64);
        if (valid) {
            const int pos = base + (int)__popcll(bal & ((1ull << lane) - 1ull));
            vlist[pos] = t;
        }
    }
    __syncthreads();

    const int n    = vcnt;
    const int npad = (n + 15) & ~15;   // mult of 16 (dup window 0; max idempotent)

    // Phase B: build stride-4 windows straight from global:
    //   xc[half*4+c][4j+k] = x[b, l_j+k, f0+half*4+c], k=0..2 (slot 3 = pad).
    for (int item = t; item < npad * 8; item += NTHR) {
        const int j    = item >> 3;
        const int k    = (item >> 1) & 3;
        const int half = item & 1;
        if (k == 3) continue;
        const int l = (j < n) ? vlist[j] : vlist[0];
        const float4 g = *reinterpret_cast<const float4*>(
            x + ((size_t)b * V_ + l + k) * F_ + f0 + half * 4);
        const int col = 4 * j + k;
        xc[half * 4 + 0][col] = g.x;
        xc[half * 4 + 1][col] = g.y;
        xc[half * 4 + 2][col] = g.z;
        xc[half * 4 + 3][col] = g.w;
    }
    __syncthreads();

    // Weights repacked into h-pairs (memory layout [h][k]).
    v2f wp0[8], wp1[8], wp2[8], bpk[8], mpk[8];
#pragma unroll
    for (int p = 0; p < 8; ++p) {
        wp0[p] = (v2f){wt[6 * p + 0], wt[6 * p + 3]};
        wp1[p] = (v2f){wt[6 * p + 1], wt[6 * p + 4]};
        wp2[p] = (v2f){wt[6 * p + 2], wt[6 * p + 5]};
        bpk[p] = (v2f){bsc[2 * p], bsc[2 * p + 1]};
        mpk[p] = (v2f){NEG_INF_F, NEG_INF_F};
    }

    const float4* xq = reinterpret_cast<const float4*>(&xc[f_local][0]);

#define PROCQ(Q)                                                              \
    do {                                                                      \
        const v2f X0 = (v2f){(Q).x, (Q).x};                                   \
        const v2f X1 = (v2f){(Q).y, (Q).y};                                   \
        const v2f X2 = (v2f){(Q).z, (Q).z};                                   \
        _Pragma("unroll")                                                     \
        for (int p = 0; p < 8; ++p) {                                         \
            const v2f c = __builtin_elementwise_fma(X0, wp0[p],               \
                          __builtin_elementwise_fma(X1, wp1[p],               \
                          __builtin_elementwise_fma(X2, wp2[p], bpk[p])));    \
            mpk[p] = __builtin_elementwise_max(mpk[p], c);                    \
        }                                                                     \
    } while (0)

    // Main loop: 1 conflict-free ds_read_b128 per window, lane handles
    // windows l_lane, l_lane+4, ... ; 4 reads batched per 16-window step.
    for (int u = 0; u < npad; u += 16) {
        const int i0 = u + l_lane;
        const float4 q0 = xq[i0];
        const float4 q1 = xq[i0 + 4];
        const float4 q2 = xq[i0 + 8];
        const float4 q3 = xq[i0 + 12];
        PROCQ(q0);
        PROCQ(q1);
        PROCQ(q2);
        PROCQ(q3);
    }
#undef PROCQ

    // Reduce across the 4 l-lanes (same (f,h0)).
#pragma unroll
    for (int p = 0; p < 8; ++p) {
        float a = __shfl_xor(mpk[p].x, 1, 64);
        float c = __shfl_xor(mpk[p].y, 1, 64);
        mpk[p].x = fmaxf(mpk[p].x, a);
        mpk[p].y = fmaxf(mpk[p].y, c);
        a = __shfl_xor(mpk[p].x, 2, 64);
        c = __shfl_xor(mpk[p].y, 2, 64);
        mpk[p].x = fmaxf(mpk[p].x, a);
        mpk[p].y = fmaxf(mpk[p].y, c);
    }

    // l_lane j writes h0+4j .. h0+4j+3 (pairs 2j, 2j+1). Wave covers 2 full
    // f-rows of 128 h contiguously -> perfectly coalesced.
    float* op = out + ((size_t)b * F_ + f) * H_ + h0 + l_lane * 4;
    const int pb = l_lane * 2;
    *reinterpret_cast<float4*>(op) =
        make_float4(mpk[pb].x, mpk[pb].y, mpk[pb + 1].x, mpk[pb + 1].y);
}

extern "C" void kernel_launch(void* const* d_in, const int* in_sizes, int n_in,
                              void* d_out, int out_size, void* d_ws, size_t ws_size,
                              hipStream_t stream) {
    const float* x    = (const float*)d_in[0];  // input_visit
    const int*   mask = (const int*)d_in[1];    // visit_mask
    const float* w    = (const float*)d_in[2];  // conv_w
    const float* bias = (const float*)d_in[3];  // conv_b
    float* out = (float*)d_out;

    const int grid = B_ * (F_ / FG);  // 1024
    fve_kernel<<<grid, NTHR, 0, stream>>>(x, mask, w, bias, out);
}

// Round 10
// 17.782 us; speedup vs baseline: 1.1283x; 1.0298x over previous
//
#include <hip/hip_runtime.h>

// FeatureViewEncoder: per-feature Conv1d(1,H,3) + mask + max-over-time.
// out[b,f,h] = max_{l: mask[b,l]!=0} ( sum_k x[b,l+k,f]*w[f,h,k] + bias[f,h] ), else -1e9.
//
// R10 = R6 + HPT=16 with occupancy pinned:
//  - __launch_bounds__(256,4): force <=128 VGPR so 4 blocks/CU survive
//    (R7/R9's regression: HPT=16 register bloat silently halved occupancy).
//  - wave = 2f x 8h x 4l: 8 distinct addrs per ds_read_b128 -> 416 LDS
//    instrs/CU (R6: 832), below the 2.8us VALU floor.
//  - WSTR % 32 == 16: f_sub 0/1 -> banks 0-15 / 16-31; 4 l-lane quads tile
//    each half -> conflict-free.
//  - weights loaded AFTER the last barrier, repacked in 4 chunks (peak
//    liveness ~100 regs); ballot compaction (no 99-deep serial atomic).

#define NEG_INF_F (-1e9f)

typedef float v2f __attribute__((ext_vector_type(2)));

constexpr int B_ = 128;
constexpr int V_ = 200;
constexpr int F_ = 64;
constexpr int H_ = 128;
constexpr int L_ = V_ - 3 + 1;   // 198

constexpr int NTHR = 256;
constexpr int FG   = 8;                    // features per block
constexpr int HPT  = 16;                   // h-outputs per thread (8 packed pairs)
constexpr int MAXW = (L_ + 7) & ~7;        // 200: max windows, mult of 8
constexpr int WSTR = 4 * MAXW + 16;        // 816 floats; 816%32==16, 16B-aligned

__global__ __launch_bounds__(NTHR, 4)
void fve_kernel(const float* __restrict__ x,     // [B,V,F]
                const int*   __restrict__ mask,  // [B,1,L]
                const float* __restrict__ w,     // [F,H,K]
                const float* __restrict__ bias,  // [F,H]
                float* __restrict__ out)         // [B,F,H]
{
    __shared__ __align__(16) float xc[FG][WSTR];  // compacted windows: xc[f][4j+k]
    __shared__ int vlist[MAXW];
    __shared__ int vcnt;

    const int b  = blockIdx.x >> 3;        // grid = B * (F/FG) = 1024
    const int f0 = (blockIdx.x & 7) * FG;
    const int t  = threadIdx.x;
    const int lane = t & 63;

    if (t == 0) vcnt = 0;
    __syncthreads();

    // Phase A: ballot-compaction of valid time-steps (order irrelevant for max).
    {
        const bool valid = (t < L_) && (mask[b * L_ + t] != 0);
        const unsigned long long bal = __ballot(valid);
        int base = 0;
        if (lane == 0) base = atomicAdd(&vcnt, __popcll(bal));
        base = __shfl(base, 0, 64);
        if (valid) {
            const int pos = base + (int)__popcll(bal & ((1ull << lane) - 1ull));
            vlist[pos] = t;
        }
    }
    __syncthreads();

    const int n    = vcnt;
    const int npad = (n + 7) & ~7;   // mult of 8 (dup window 0; max idempotent)

    // Phase B: build stride-4 windows straight from global:
    //   xc[half*4+c][4j+k] = x[b, l_j+k, f0+half*4+c], k=0..2 (slot 3 = pad).
    for (int item = t; item < npad * 8; item += NTHR) {
        const int j    = item >> 3;
        const int k    = (item >> 1) & 3;
        const int half = item & 1;
        if (k == 3) continue;
        const int l = (j < n) ? vlist[j] : vlist[0];
        const float4 g = *reinterpret_cast<const float4*>(
            x + ((size_t)b * V_ + l + k) * F_ + f0 + half * 4);
        const int col = 4 * j + k;
        xc[half * 4 + 0][col] = g.x;
        xc[half * 4 + 1][col] = g.y;
        xc[half * 4 + 2][col] = g.z;
        xc[half * 4 + 3][col] = g.w;
    }
    __syncthreads();

    // Thread map (main loop): wave = 2 f-rows x 8 h-lanes x 4 l-lanes.
    const int f_sub   = lane >> 5;             // 0..1
    const int h_lane  = (lane >> 2) & 7;       // 0..7
    const int l_lane  = lane & 3;              // 0..3
    const int f_local = (t >> 6) * 2 + f_sub;  // 0..7 (f_sub == parity)
    const int f       = f0 + f_local;
    const int h0      = h_lane * HPT;          // 0,16,...,112

    // Weights for h0..h0+15 (48 contiguous floats, layout [h][k]) + 16 bias.
    // Load+repack in 4 chunks of 12 floats to cap register liveness.
    const float* wp = w + ((size_t)f * H_ + h0) * 3;
    const float* bp = bias + (size_t)f * H_ + h0;

    v2f wp0[8], wp1[8], wp2[8], bpk[8], mpk[8];
#pragma unroll
    for (int c = 0; c < 4; ++c) {              // chunk c covers pairs 2c, 2c+1
        const float4 a = *reinterpret_cast<const float4*>(wp + 12 * c);
        const float4 d = *reinterpret_cast<const float4*>(wp + 12 * c + 4);
        const float4 e = *reinterpret_cast<const float4*>(wp + 12 * c + 8);
        const float4 bv = *reinterpret_cast<const float4*>(bp + 4 * c);
        const int p = 2 * c;
        // floats: a={w[0],w[1],w[2], w[3]}, d={w[4],w[5], w[6],w[7]}, e={w[8], w[9],w[10],w[11]}
        // pair p   : h=4c+0,4c+1 -> taps (a.x,d.x) (a.y,d.y?) ... layout [h][k]:
        // h even: k0=a.x k1=a.y k2=a.z ; h odd: k0=a.w k1=d.x k2=d.y
        wp0[p]     = (v2f){a.x, a.w};
        wp1[p]     = (v2f){a.y, d.x};
        wp2[p]     = (v2f){a.z, d.y};
        wp0[p + 1] = (v2f){d.z, e.y};
        wp1[p + 1] = (v2f){d.w, e.z};
        wp2[p + 1] = (v2f){e.x, e.w};
        bpk[p]     = (v2f){bv.x, bv.y};
        bpk[p + 1] = (v2f){bv.z, bv.w};
        mpk[p]     = (v2f){NEG_INF_F, NEG_INF_F};
        mpk[p + 1] = (v2f){NEG_INF_F, NEG_INF_F};
    }

    const float4* xq = reinterpret_cast<const float4*>(&xc[f_local][0]);

#define PROCQ(Q)                                                              \
    do {                                                                      \
        const v2f X0 = (v2f){(Q).x, (Q).x};                                   \
        const v2f X1 = (v2f){(Q).y, (Q).y};                                   \
        const v2f X2 = (v2f){(Q).z, (Q).z};                                   \
        _Pragma("unroll")                                                     \
        for (int p = 0; p < 8; ++p) {                                         \
            const v2f c = __builtin_elementwise_fma(X0, wp0[p],               \
                          __builtin_elementwise_fma(X1, wp1[p],               \
                          __builtin_elementwise_fma(X2, wp2[p], bpk[p])));    \
            mpk[p] = __builtin_elementwise_max(mpk[p], c);                    \
        }                                                                     \
    } while (0)

    // Main loop: conflict-free ds_read_b128; lane handles windows
    // l_lane, l_lane+4, ...; 2 reads batched per 8-window step.
    for (int u = 0; u < npad; u += 8) {
        const int i0 = u + l_lane;
        const float4 q0 = xq[i0];
        const float4 q1 = xq[i0 + 4];
        PROCQ(q0);
        PROCQ(q1);
    }
#undef PROCQ

    // Reduce across the 4 l-lanes (same (f,h0)).
#pragma unroll
    for (int p = 0; p < 8; ++p) {
        float a = __shfl_xor(mpk[p].x, 1, 64);
        float c = __shfl_xor(mpk[p].y, 1, 64);
        mpk[p].x = fmaxf(mpk[p].x, a);
        mpk[p].y = fmaxf(mpk[p].y, c);
        a = __shfl_xor(mpk[p].x, 2, 64);
        c = __shfl_xor(mpk[p].y, 2, 64);
        mpk[p].x = fmaxf(mpk[p].x, a);
        mpk[p].y = fmaxf(mpk[p].y, c);
    }

    // l_lane j writes h0+4j..h0+4j+3 (pairs 2j, 2j+1): coalesced float4s.
    float* op = out + ((size_t)b * F_ + f) * H_ + h0 + l_lane * 4;
    const int pb = l_lane * 2;
    *reinterpret_cast<float4*>(op) =
        make_float4(mpk[pb].x, mpk[pb].y, mpk[pb + 1].x, mpk[pb + 1].y);
}

extern "C" void kernel_launch(void* const* d_in, const int* in_sizes, int n_in,
                              void* d_out, int out_size, void* d_ws, size_t ws_size,
                              hipStream_t stream) {
    const float* x    = (const float*)d_in[0];  // input_visit
    const int*   mask = (const int*)d_in[1];    // visit_mask
    const float* w    = (const float*)d_in[2];  // conv_w
    const float* bias = (const float*)d_in[3];  // conv_b
    float* out = (float*)d_out;

    const int grid = B_ * (F_ / FG);  // 1024
    fve_kernel<<<grid, NTHR, 0, stream>>>(x, mask, w, bias, out);
}